// Round 11
// baseline (415.360 us; speedup 1.0000x reference)
//
#include <hip/hip_runtime.h>
#include <stdint.h>

typedef __attribute__((ext_vector_type(4))) int i32x4;

// ---------------------------------------------------------------------------
// Kernel 1: per-row symmetric weight quantization — R10 rewrite.
// One WAVE per row (4 rows / 256-thread block): reduction is a 6-step
// __shfl_xor butterfly (no LDS, no __syncthreads), and the per-element
// division is replaced by one 127/am reciprocal per row + multiplies.
// row_scales value (am/127, fp32 div) is bit-identical to reference.
// Assumes K == 4096 (16 float4 per lane).
// ---------------------------------------------------------------------------
__global__ __launch_bounds__(256) void wquant_kernel(
    const float* __restrict__ W, int8_t* __restrict__ Wq,
    float* __restrict__ row_scales, int* __restrict__ wsum_out, int K)
{
    const int lane = threadIdx.x & 63;
    const int row  = blockIdx.x * 4 + (threadIdx.x >> 6);
    const float4* Wrow = (const float4*)(W + (size_t)row * K);
    float4 v[16];
    float am = 0.f;
#pragma unroll
    for (int j = 0; j < 16; ++j) {
        v[j] = Wrow[j * 64 + lane];
        am = fmaxf(am, fmaxf(fmaxf(fabsf(v[j].x), fabsf(v[j].y)),
                             fmaxf(fabsf(v[j].z), fabsf(v[j].w))));
    }
#pragma unroll
    for (int off = 32; off >= 1; off >>= 1)
        am = fmaxf(am, __shfl_xor(am, off));
    const float scale = am / 127.0f;              // matches np exactly
    const float sinv  = (scale > 0.f) ? 127.0f / am : 0.f;

    int lsum = 0;
    int* qrow = (int*)(Wq + (size_t)row * K);
#pragma unroll
    for (int j = 0; j < 16; ++j) {
        const int q0 = (int)fminf(fmaxf(rintf(v[j].x * sinv), -127.f), 127.f);
        const int q1 = (int)fminf(fmaxf(rintf(v[j].y * sinv), -127.f), 127.f);
        const int q2 = (int)fminf(fmaxf(rintf(v[j].z * sinv), -127.f), 127.f);
        const int q3 = (int)fminf(fmaxf(rintf(v[j].w * sinv), -127.f), 127.f);
        qrow[j * 64 + lane] = (q0 & 255) | ((q1 & 255) << 8) |
                              ((q2 & 255) << 16) | ((q3 & 255) << 24);
        lsum += q0 + q1 + q2 + q3;
    }
#pragma unroll
    for (int off = 32; off >= 1; off >>= 1) lsum += __shfl_xor(lsum, off);
    if (lane == 0) {
        wsum_out[row]   = lsum;
        row_scales[row] = scale;
    }
}

// ---------------------------------------------------------------------------
// Kernel 2: per-token asymmetric activation quantization — R10 rewrite.
// One wave per row; shfl_xor butterfly min/max; scale and zp computed with
// exact fp32 divisions (2 per row, as reference); per-element quant uses
// one 1/scale reciprocal + multiply (<=1 ulp from reference; harmless).
// ---------------------------------------------------------------------------
__global__ __launch_bounds__(256) void xquant_kernel(
    const float* __restrict__ X, const float* __restrict__ cmin,
    const float* __restrict__ cmax, int8_t* __restrict__ Xq,
    float* __restrict__ col_scales, float* __restrict__ zps, int K)
{
    const int lane = threadIdx.x & 63;
    const int row  = blockIdx.x * 4 + (threadIdx.x >> 6);
    const float4* Xrow = (const float4*)(X + (size_t)row * K);
    const float4* lo4  = (const float4*)cmin;
    const float4* hi4  = (const float4*)cmax;
    float4 v[16];
    float mn = 1e30f, mx = -1e30f;
#pragma unroll
    for (int j = 0; j < 16; ++j) {
        float4 x  = Xrow[j * 64 + lane];
        float4 lo = lo4[j * 64 + lane];
        float4 hi = hi4[j * 64 + lane];
        x.x = fminf(fmaxf(x.x, lo.x), hi.x);
        x.y = fminf(fmaxf(x.y, lo.y), hi.y);
        x.z = fminf(fmaxf(x.z, lo.z), hi.z);
        x.w = fminf(fmaxf(x.w, lo.w), hi.w);
        v[j] = x;
        mn = fminf(mn, fminf(fminf(x.x, x.y), fminf(x.z, x.w)));
        mx = fmaxf(mx, fmaxf(fmaxf(x.x, x.y), fmaxf(x.z, x.w)));
    }
#pragma unroll
    for (int off = 32; off >= 1; off >>= 1) {
        mn = fminf(mn, __shfl_xor(mn, off));
        mx = fmaxf(mx, __shfl_xor(mx, off));
    }
    float scale = (mx - mn) / 255.0f;             // matches np exactly
    if (!(scale > 0.f)) scale = 1.0f;
    const float zpf  = rintf(-128.0f - mn / scale);
    const float sinv = 1.0f / scale;

    int* qrow = (int*)(Xq + (size_t)row * K);
#pragma unroll
    for (int j = 0; j < 16; ++j) {
        const int q0 = (int)fminf(fmaxf(rintf(v[j].x * sinv) + zpf, -128.f), 127.f);
        const int q1 = (int)fminf(fmaxf(rintf(v[j].y * sinv) + zpf, -128.f), 127.f);
        const int q2 = (int)fminf(fmaxf(rintf(v[j].z * sinv) + zpf, -128.f), 127.f);
        const int q3 = (int)fminf(fmaxf(rintf(v[j].w * sinv) + zpf, -128.f), 127.f);
        qrow[j * 64 + lane] = (q0 & 255) | ((q1 & 255) << 8) |
                              ((q2 & 255) << 16) | ((q3 & 255) << 24);
    }
    if (lane == 0) { col_scales[row] = scale; zps[row] = zpf; }
}

// ---------------------------------------------------------------------------
// Kernel 3: int8 GEMM, 256x256 tile, BK=128 bytes, 8-phase schedule (T3+T4+T5)
// UNCHANGED from R10's verified kernel (passed, 166 us, MfmaUtil 35.8%,
// 0 bank conflicts). See R3 fix + R7/R8 desk-audit notes in history.
// ---------------------------------------------------------------------------

__device__ __forceinline__ void gload16(const int8_t* g, const uint8_t* l) {
    __builtin_amdgcn_global_load_lds(
        (const __attribute__((address_space(1))) void*)g,
        (__attribute__((address_space(3))) void*)l, 16, 0, 0);
}

__device__ __forceinline__ void bar() {
    asm volatile("" ::: "memory");
    __builtin_amdgcn_s_barrier();
    asm volatile("" ::: "memory");
}

#define VMW(N) asm volatile("s_waitcnt vmcnt(" #N ")" ::: "memory")

#define RD_A(mh, db)                                                          \
    { _Pragma("unroll") for (int f = 0; f < 4; ++f) {                         \
        afr[mh][f][0] = *(const i32x4*)(aRd + (db) + (mh)*16384 + f*256);     \
        afr[mh][f][1] = *(const i32x4*)(aRd + (db) + (mh)*16384 + 8192 + f*256); } }

#define RD_B(nh, db)                                                          \
    { _Pragma("unroll") for (int g = 0; g < 2; ++g) {                         \
        bfr[g][0] = *(const i32x4*)(bRd + (db) + (nh)*16384 + g*256);         \
        bfr[g][1] = *(const i32x4*)(bRd + (db) + (nh)*16384 + 8192 + g*256); } }

#define MM(mh, nh)                                                            \
    { __builtin_amdgcn_s_setprio(1);                                          \
      _Pragma("unroll") for (int f = 0; f < 4; ++f)                           \
      _Pragma("unroll") for (int g = 0; g < 2; ++g) {                         \
        acc[(mh)*4+f][(nh)*2+g] = __builtin_amdgcn_mfma_i32_16x16x64_i8(      \
            afr[mh][f][0], bfr[g][0], acc[(mh)*4+f][(nh)*2+g], 0, 0, 0);      \
        acc[(mh)*4+f][(nh)*2+g] = __builtin_amdgcn_mfma_i32_16x16x64_i8(      \
            afr[mh][f][1], bfr[g][1], acc[(mh)*4+f][(nh)*2+g], 0, 0, 0); }    \
      __builtin_amdgcn_s_setprio(0); }

#define STG_A(db, h, ktv)                                                     \
    { const int8_t* g_ = aSt + (size_t)(h)*128*Ks + (size_t)(ktv)*128;        \
      gload16(g_,      lSt + (db) + (h)*16384);                               \
      gload16(g_ + 64, lSt + (db) + (h)*16384 + 8192); }

#define STG_B(db, h, ktv)                                                     \
    { const int8_t* g_ = bSt + (size_t)(h)*128*Ks + (size_t)(ktv)*128;        \
      gload16(g_,      lSt + (db) + 32768 + (h)*16384);                       \
      gload16(g_ + 64, lSt + (db) + 32768 + (h)*16384 + 8192); }

__global__ __launch_bounds__(512, 2) void gemm_i8_kernel(
    const int8_t* __restrict__ Aq,   // [M_tok][K]
    const int8_t* __restrict__ Bq,   // [N_out][K]
    const float* __restrict__ col_scales, const float* __restrict__ zps,
    const int* __restrict__ wsum, const float* __restrict__ row_scales,
    const float* __restrict__ bias, float* __restrict__ out,
    int Nout, int K)
{
    __shared__ uint8_t lds[131072];
    const int t = threadIdx.x;
    const int lane = t & 63;
    const int w = t >> 6;              // 0..7
    const int wr = w >> 2;             // 0..1  (M)
    const int wc = w & 3;              // 0..3  (N)
    const int l15 = lane & 15, lhi = lane >> 4;
    const size_t Ks = (size_t)K;
    const int aRow0 = blockIdx.y * 256;
    const int bRow0 = blockIdx.x * 256;

    const int8_t* aSt = Aq + (size_t)(aRow0 + (t & 127)) * Ks + ((t >> 7) * 16);
    const int8_t* bSt = Bq + (size_t)(bRow0 + (t & 127)) * Ks + ((t >> 7) * 16);
    const uint8_t* lSt = lds + t * 16;
    const uint8_t* aRd = lds + lhi * 2048 + (wr * 64 + l15) * 16;
    const uint8_t* bRd = lds + 32768 + lhi * 2048 + (wc * 32 + l15) * 16;

    i32x4 acc[8][4] = {};
    i32x4 afr[2][4][2], bfr[2][2];

    // ---- prologue: kt0 all 4 halves -> bufA; kt1 B0,A0 -> bufB ----
    STG_A(0, 0, 0); STG_A(0, 1, 0); STG_B(0, 0, 0); STG_B(0, 1, 0);
    STG_B(65536, 0, 1); STG_A(65536, 0, 1);
    VMW(4);            // bufA's 8 loads landed; bufB's 4 still in flight
    bar();

    const int nit = (K >> 8);          // iterations of 2 K-tiles
    for (int i2 = 0; i2 < nit - 1; ++i2) {
        const int kB1 = 2 * i2 + 1, kA = 2 * i2 + 2, kB3 = 2 * i2 + 3;
        RD_A(0, 0); RD_B(0, 0); STG_A(65536, 1, kB1); bar(); MM(0, 0); bar();
        RD_A(1, 0);             STG_B(65536, 1, kB1); bar(); MM(1, 0); bar();
        RD_B(1, 0);             STG_B(0, 0, kA);      bar(); MM(0, 1); bar();
                                STG_A(0, 0, kA);      bar(); MM(1, 1); VMW(4); bar();
        RD_A(0, 65536); RD_B(0, 65536); STG_A(0, 1, kA); bar(); MM(0, 0); bar();
        RD_A(1, 65536);         STG_B(0, 1, kA);      bar(); MM(1, 0); bar();
        RD_B(1, 65536);         STG_B(65536, 0, kB3); bar(); MM(0, 1); bar();
                                STG_A(65536, 0, kB3); bar(); MM(1, 1); VMW(4); bar();
    }
    // ---- final iteration: still stage bufB.A1/B1 <- kLast (read by ph6/ph7);
    //      drop only the kt+2/kt+3 lookahead stages; full drain at ph4 ----
    {
        const int kLast = 2 * nit - 1;
        RD_A(0, 0); RD_B(0, 0); STG_A(65536, 1, kLast); bar(); MM(0, 0); bar();
        RD_A(1, 0);             STG_B(65536, 1, kLast); bar(); MM(1, 0); bar();
        RD_B(1, 0);             bar(); MM(0, 1); bar();
                                bar(); MM(1, 1); VMW(0); bar();
        RD_A(0, 65536); RD_B(0, 65536); bar(); MM(0, 0); bar();
        RD_A(1, 65536);         bar(); MM(1, 0); bar();
        RD_B(1, 65536);         bar(); MM(0, 1); bar();
                                bar(); MM(1, 1);
    }

    // ---- epilogue: Y = (acc - zp*wsum) * cs * rs + bias ----
    const int ocol0 = bRow0 + wc * 32 + l15;
    float rs_[4], bi_[4];
    int ws_[4];
#pragma unroll
    for (int n = 0; n < 4; ++n) {
        const int oc = ocol0 + (n >> 1) * 128 + (n & 1) * 16;
        rs_[n] = row_scales[oc];
        bi_[n] = bias[oc];
        ws_[n] = wsum[oc];
    }
#pragma unroll
    for (int m = 0; m < 8; ++m) {
        const int trowb = aRow0 + (m >> 2) * 128 + wr * 64 + (m & 3) * 16 + lhi * 4;
#pragma unroll
        for (int r = 0; r < 4; ++r) {
            const int token = trowb + r;                 // C/D: row=(l>>4)*4+reg
            const float cs = col_scales[token];
            const int zv = (int)zps[token];
            float* orow = out + (size_t)token * Nout + ocol0;
#pragma unroll
            for (int n = 0; n < 4; ++n) {
                const int a = acc[m][n][r] - zv * ws_[n];
                orow[(n >> 1) * 128 + (n & 1) * 16] = (float)a * cs * rs_[n] + bi_[n];
            }
        }
    }
}

// ---------------------------------------------------------------------------
extern "C" void kernel_launch(void* const* d_in, const int* in_sizes, int n_in,
                              void* d_out, int out_size, void* d_ws, size_t ws_size,
                              hipStream_t stream)
{
    const float* x    = (const float*)d_in[0];
    const float* W    = (const float*)d_in[1];
    const float* bias = (const float*)d_in[2];
    const float* cmin = (const float*)d_in[3];
    const float* cmax = (const float*)d_in[4];
    float* out = (float*)d_out;

    const int D_IN  = in_sizes[3];               // 4096
    const int D_OUT = in_sizes[2];               // 4096
    const int Ntok  = in_sizes[0] / D_IN;        // 8192

    uint8_t* ws = (uint8_t*)d_ws;
    int8_t* Wq = (int8_t*)ws;
    int8_t* Xq = (int8_t*)(ws + (size_t)D_OUT * D_IN);
    float* row_scales = (float*)(ws + (size_t)D_OUT * D_IN + (size_t)Ntok * D_IN);
    int*   wsum       = (int*)(row_scales + D_OUT);
    float* col_scales = (float*)(wsum + D_OUT);
    float* zps        = col_scales + Ntok;

    wquant_kernel<<<D_OUT / 4, 256, 0, stream>>>(W, Wq, row_scales, wsum, D_IN);
    xquant_kernel<<<Ntok / 4, 256, 0, stream>>>(x, cmin, cmax, Xq, col_scales, zps, D_IN);

    dim3 grid(D_OUT / 256, Ntok / 256);
    gemm_i8_kernel<<<grid, dim3(512), 0, stream>>>(
        Xq, Wq, col_scales, zps, wsum, row_scales, bias, out, D_OUT, D_IN);
}